// Round 7
// baseline (963.254 us; speedup 1.0000x reference)
//
#include <hip/hip_runtime.h>
#include <math.h>

#define NNODES 100000
#define NEDGES 1600000
#define NREL   4
#define DIN    38
#define HID    64
#define NGRAPH 1000
#define NSEG   (NNODES * NREL)          // 400000
#define NSCANB ((NSEG + 1023) / 1024)   // 391

__device__ __forceinline__ float wsum64(float v) {
    #pragma unroll
    for (int o = 32; o; o >>= 1) v += __shfl_xor(v, o);
    return v;
}

__device__ __forceinline__ void ln_group_reduce(float& s) {
    s += __shfl_xor(s, 1);
    s += __shfl_xor(s, 2);
    s += __shfl_xor(s, 4);
    s += __shfl_xor(s, 8);
}

// ---------------------------------------------------------------------------
// counts: cnt[node*R+rel] edge counts, gcnt[g] nodes per graph
// ---------------------------------------------------------------------------
__global__ __launch_bounds__(256) void count_kernel(
    const int* __restrict__ ei, const int* __restrict__ et,
    const int* __restrict__ batch, int* __restrict__ cnt,
    int* __restrict__ gcnt) {
    int i = blockIdx.x * 256 + threadIdx.x;
    if (i < NEDGES) {
        int dst = ei[NEDGES + i];
        atomicAdd(&cnt[dst * NREL + et[i]], 1);
    }
    if (i < NNODES) {
        atomicAdd(&gcnt[batch[i]], 1);
    }
}

// ---------------------------------------------------------------------------
// scan1: per-1024-chunk exclusive scan of cnt -> excl, chunk totals -> bsum
// ---------------------------------------------------------------------------
__global__ __launch_bounds__(256) void scan1_kernel(
    const int* __restrict__ cnt, int* __restrict__ excl, int* __restrict__ bsum) {
    __shared__ int tmp[256];
    int tid = threadIdx.x;
    int base = blockIdx.x * 1024 + tid * 4;
    int v0 = 0, v1 = 0, v2 = 0, v3 = 0;
    if (base + 0 < NSEG) v0 = cnt[base + 0];
    if (base + 1 < NSEG) v1 = cnt[base + 1];
    if (base + 2 < NSEG) v2 = cnt[base + 2];
    if (base + 3 < NSEG) v3 = cnt[base + 3];
    int s = v0 + v1 + v2 + v3;
    tmp[tid] = s;
    __syncthreads();
    for (int off = 1; off < 256; off <<= 1) {
        int t = (tid >= off) ? tmp[tid - off] : 0;
        __syncthreads();
        tmp[tid] += t;
        __syncthreads();
    }
    if (tid == 255) bsum[blockIdx.x] = tmp[255];
    int run = tmp[tid] - s;
    if (base + 0 < NSEG) excl[base + 0] = run; run += v0;
    if (base + 1 < NSEG) excl[base + 1] = run; run += v1;
    if (base + 2 < NSEG) excl[base + 2] = run; run += v2;
    if (base + 3 < NSEG) excl[base + 3] = run;
}

// scan2: exclusive scan of bsum[NSCANB] in one block
__global__ __launch_bounds__(512) void scan2_kernel(int* __restrict__ bsum) {
    __shared__ int tmp[512];
    int tid = threadIdx.x;
    int v = (tid < NSCANB) ? bsum[tid] : 0;
    tmp[tid] = v;
    __syncthreads();
    for (int off = 1; off < 512; off <<= 1) {
        int t = (tid >= off) ? tmp[tid - off] : 0;
        __syncthreads();
        tmp[tid] += t;
        __syncthreads();
    }
    if (tid < NSCANB) bsum[tid] = tmp[tid] - v;
}

// ---------------------------------------------------------------------------
// place: CSR bucket fill. esrc entry = plain src node id
// ---------------------------------------------------------------------------
__global__ __launch_bounds__(256) void place_kernel(
    const int* __restrict__ ei, const int* __restrict__ et,
    const int* __restrict__ excl, const int* __restrict__ bsum,
    int* __restrict__ fill, int* __restrict__ esrc) {
    int e = blockIdx.x * 256 + threadIdx.x;
    if (e >= NEDGES) return;
    int seg = ei[NEDGES + e] * NREL + et[e];
    int pos = excl[seg] + bsum[seg >> 10] + atomicAdd(&fill[seg], 1);
    esrc[pos] = ei[e];
}

// ---------------------------------------------------------------------------
// fused layer: 64-node tile, 1024 threads (16 waves).
// Gather: one node per 16-lane group (lane=(node r=tid>>4, ch-quarter cl)).
//   Node's 4 rel segments are contiguous in CSR; process each with a static
//   accumulator a{0..3}[4] (no rel branches). 16-edge chunks staged via one
//   esrc load + in-group shfl; per edge: float4 gather from x (L3-resident).
// GEMM: 4 rel passes + root (+res if L0): stage means/x-tile + W into LDS,
//   1x4 micro-tile (row r, cols cl*4..+3), K=F.
// Epilogue: relu(conv+bias)+residual(+resb if L0), LN over 16-lane group,
//   store float4 (or pooled atomics if POOL).
// ---------------------------------------------------------------------------
template <int F, bool L0, bool POOL>
__global__ __launch_bounds__(1024, 4) void fused_kernel(
    const float* __restrict__ x, const float* __restrict__ W,
    const float* __restrict__ root, const float* __restrict__ resw,
    const float* __restrict__ bias, const float* __restrict__ resb,
    const float* __restrict__ lng, const float* __restrict__ lnb,
    const int* __restrict__ cnt, const int* __restrict__ excl,
    const int* __restrict__ bsum, const int* __restrict__ esrc,
    const int* __restrict__ batch, float* __restrict__ dst) {
    __shared__ float As[64][68];
    __shared__ float Ws[64][68];
    const int tid   = threadIdx.x;
    const int nbase = blockIdx.x * 64;
    const int r     = tid >> 4;       // node-local index / output row (0..63)
    const int cl    = tid & 15;       // channel quarter
    const int lane  = tid & 63;
    const int gbase = lane & 48;      // first lane of this 16-lane group

    const int n  = nbase + r;
    const int nc = (n < NNODES) ? n : (NNODES - 1);

    // ---- gather phase ----
    int myc = 0, myb = 0;
    if (cl < 4) {
        int s = nc * 4 + cl;
        myc = cnt[s];
        myb = excl[s] + bsum[s >> 10];
    }
    const int c0 = __shfl(myc, gbase + 0);
    const int c1 = __shfl(myc, gbase + 1);
    const int c2 = __shfl(myc, gbase + 2);
    const int c3 = __shfl(myc, gbase + 3);
    const int b0 = __shfl(myb, gbase + 0);
    const int e1 = c0, e2 = e1 + c1, e3 = e2 + c2, e4 = e3 + c3;

    float a0[4] = {}, a1[4] = {}, a2[4] = {}, a3[4] = {};

#define GATHER_SEG(ACC, LOA, HIA)                                            \
    {                                                                        \
        int lo = (LOA) - base; if (lo < 0) lo = 0;                           \
        int hi = (HIA) - base; if (hi > 16) hi = 16;                         \
        for (int i = lo; i < hi; ++i) {                                      \
            int src = __shfl(ev, gbase + i);                                 \
            if (F == 64) {                                                   \
                const float4 v = *(const float4*)&x[(size_t)src * 64 + cl * 4]; \
                ACC[0] += v.x; ACC[1] += v.y; ACC[2] += v.z; ACC[3] += v.w;  \
            } else {                                                         \
                const float* px = &x[(size_t)src * F + cl * 4];              \
                if (cl <= 9) { float2 v = *(const float2*)px;                \
                               ACC[0] += v.x; ACC[1] += v.y; }               \
                if (cl <= 8) { float2 v = *(const float2*)(px + 2);          \
                               ACC[2] += v.x; ACC[3] += v.y; }               \
            }                                                                \
        }                                                                    \
    }

    for (int base = 0; base < e4; base += 16) {
        int ev = (base + cl < e4) ? esrc[b0 + base + cl] : 0;
        GATHER_SEG(a0, 0,  e1)
        GATHER_SEG(a1, e1, e2)
        GATHER_SEG(a2, e2, e3)
        GATHER_SEG(a3, e3, e4)
    }
#undef GATHER_SEG

    {
        const float i0 = 1.f / fmaxf((float)c0, 1.f);
        const float i1 = 1.f / fmaxf((float)c1, 1.f);
        const float i2 = 1.f / fmaxf((float)c2, 1.f);
        const float i3 = 1.f / fmaxf((float)c3, 1.f);
        #pragma unroll
        for (int j = 0; j < 4; ++j) {
            a0[j] *= i0; a1[j] *= i1; a2[j] *= i2; a3[j] *= i3;
        }
    }

    // ---- GEMM phase ----
    float acc[4]  = {};
    float accB[4] = {};

    #pragma unroll
    for (int rel = 0; rel < 4; ++rel) {
        __syncthreads();
        const float* ar = (rel == 0) ? a0 : (rel == 1) ? a1 : (rel == 2) ? a2 : a3;
        #pragma unroll
        for (int jj = 0; jj < 4; ++jj)
            As[cl * 4 + jj][r] = ar[jj];
        const float* wsrc = W + (size_t)rel * F * 64;
        for (int idx = tid; idx < F * 64; idx += 1024)
            Ws[idx >> 6][idx & 63] = wsrc[idx];
        __syncthreads();
        #pragma unroll 4
        for (int k = 0; k < F; ++k) {
            const float av = As[k][r];
            const float4 wv = *(const float4*)&Ws[k][cl * 4];
            acc[0] += av * wv.x; acc[1] += av * wv.y;
            acc[2] += av * wv.z; acc[3] += av * wv.w;
        }
    }

    // root pass: As = x tile
    __syncthreads();
    for (int idx = tid; idx < 64 * F; idx += 1024) {
        int m = idx / F, k = idx - m * F;
        int nm = nbase + m; if (nm > NNODES - 1) nm = NNODES - 1;
        As[k][m] = x[(size_t)nm * F + k];
    }
    for (int idx = tid; idx < F * 64; idx += 1024)
        Ws[idx >> 6][idx & 63] = root[idx];
    __syncthreads();
    #pragma unroll 4
    for (int k = 0; k < F; ++k) {
        const float av = As[k][r];
        const float4 wv = *(const float4*)&Ws[k][cl * 4];
        acc[0] += av * wv.x; acc[1] += av * wv.y;
        acc[2] += av * wv.z; acc[3] += av * wv.w;
    }

    if (L0) {   // res pass: As unchanged (x tile), Ws = res_w
        __syncthreads();
        for (int idx = tid; idx < F * 64; idx += 1024)
            Ws[idx >> 6][idx & 63] = resw[idx];
        __syncthreads();
        #pragma unroll 4
        for (int k = 0; k < F; ++k) {
            const float av = As[k][r];
            const float4 wv = *(const float4*)&Ws[k][cl * 4];
            accB[0] += av * wv.x; accB[1] += av * wv.y;
            accB[2] += av * wv.z; accB[3] += av * wv.w;
        }
    }

    // ---- epilogue ----
    const float4 bv = *(const float4*)&bias[cl * 4];
    const float b_[4] = {bv.x, bv.y, bv.z, bv.w};
    float u[4];
    float s = 0.f;
    if (L0) {
        const float4 sv = *(const float4*)&resb[cl * 4];
        const float s2_[4] = {sv.x, sv.y, sv.z, sv.w};
        #pragma unroll
        for (int j = 0; j < 4; ++j) {
            u[j] = fmaxf(acc[j] + b_[j], 0.f) + accB[j] + s2_[j];
            s += u[j];
        }
    } else {
        const float4 rv = *(const float4*)&x[(size_t)nc * 64 + cl * 4];
        const float r_[4] = {rv.x, rv.y, rv.z, rv.w};
        #pragma unroll
        for (int j = 0; j < 4; ++j) {
            u[j] = fmaxf(acc[j] + b_[j], 0.f) + r_[j];
            s += u[j];
        }
    }
    ln_group_reduce(s);
    float mu = s * (1.f / 64.f);
    float q = 0.f;
    #pragma unroll
    for (int j = 0; j < 4; ++j) { u[j] -= mu; q += u[j] * u[j]; }
    ln_group_reduce(q);
    float inv = 1.f / sqrtf(q * (1.f / 64.f) + 1e-5f);
    const float4 gv = *(const float4*)&lng[cl * 4];
    const float4 ev2 = *(const float4*)&lnb[cl * 4];
    const float g_[4] = {gv.x, gv.y, gv.z, gv.w};
    const float e_[4] = {ev2.x, ev2.y, ev2.z, ev2.w};
    float o[4];
    #pragma unroll
    for (int j = 0; j < 4; ++j) o[j] = u[j] * inv * g_[j] + e_[j];

    if (n < NNODES) {
        if (POOL) {
            int g = batch[n];
            #pragma unroll
            for (int j = 0; j < 4; ++j)
                atomicAdd(dst + (size_t)g * 64 + cl * 4 + j, o[j]);
        } else {
            *(float4*)&dst[(size_t)n * 64 + cl * 4] =
                make_float4(o[0], o[1], o[2], o[3]);
        }
    }
}

// ---------------------------------------------------------------------------
// readout: out[g] = relu(pooled[g]/cnt @ ro_w1 + ro_b1) @ ro_w2 + ro_b2
// ---------------------------------------------------------------------------
__global__ __launch_bounds__(256) void readout_kernel(
    const float* __restrict__ pooled, const int* __restrict__ gcnt,
    const float* __restrict__ w1, const float* __restrict__ b1,
    const float* __restrict__ w2, const float* __restrict__ b2,
    float* __restrict__ out) {
    __shared__ float wl[64][64];
    int tid = threadIdx.x;
    for (int idx = tid; idx < 64 * 64; idx += 256) {
        wl[idx >> 6][idx & 63] = w1[idx];
    }
    __syncthreads();
    int wv = tid >> 6, lane = tid & 63;
    int g = blockIdx.x * 4 + wv;
    if (g >= NGRAPH) return;
    int cc = gcnt[g];
    float cf = cc > 0 ? (float)cc : 1.0f;
    float p = pooled[(size_t)g * 64 + lane] / cf;
    float acc = b1[lane];
    for (int f = 0; f < 64; ++f) {
        acc += __shfl(p, f) * wl[f][lane];
    }
    float t = fmaxf(acc, 0.f);
    float v = t * w2[lane];
    v = wsum64(v);
    if (lane == 0) out[g] = v + b2[0];
}

// ---------------------------------------------------------------------------
extern "C" void kernel_launch(void* const* d_in, const int* in_sizes, int n_in,
                              void* d_out, int out_size, void* d_ws, size_t ws_size,
                              hipStream_t stream) {
    const float* x     = (const float*)d_in[0];
    const int*   ei    = (const int*)d_in[1];
    const int*   et    = (const int*)d_in[2];
    const int*   batch = (const int*)d_in[3];
    const float* W0    = (const float*)d_in[4];
    const float* root0 = (const float*)d_in[5];
    const float* b0    = (const float*)d_in[6];
    const float* ln0g  = (const float*)d_in[7];
    const float* ln0b  = (const float*)d_in[8];
    const float* resw  = (const float*)d_in[9];
    const float* resb  = (const float*)d_in[10];
    const float* W1    = (const float*)d_in[11];
    const float* root1 = (const float*)d_in[12];
    const float* b1    = (const float*)d_in[13];
    const float* ln1g  = (const float*)d_in[14];
    const float* ln1b  = (const float*)d_in[15];
    const float* W2    = (const float*)d_in[16];
    const float* root2 = (const float*)d_in[17];
    const float* b2    = (const float*)d_in[18];
    const float* ln2g  = (const float*)d_in[19];
    const float* ln2b  = (const float*)d_in[20];
    const float* row1  = (const float*)d_in[21];
    const float* rob1  = (const float*)d_in[22];
    const float* row2  = (const float*)d_in[23];
    const float* rob2  = (const float*)d_in[24];
    float* out = (float*)d_out;

    char* ws = (char*)d_ws;
    size_t off = 0;
    int* cnt    = (int*)(ws + off); off += (size_t)NSEG * 4;            // 1.6 MB
    int* fill   = (int*)(ws + off); off += (size_t)NSEG * 4;            // 1.6 MB
    int* gcnt   = (int*)(ws + off); off += 4096;
    float* pooled = (float*)(ws + off); off += (size_t)NGRAPH * 64 * 4; // 256 KB
    size_t zero_bytes = off;                                            // ~3.46 MB
    int* excl   = (int*)(ws + off); off += (size_t)NSEG * 4;
    int* bsum   = (int*)(ws + off); off += 4096;
    int* esrc   = (int*)(ws + off); off += (size_t)NEDGES * 4;          // 6.4 MB
    float* xA   = (float*)(ws + off); off += (size_t)NNODES * 64 * 4;   // 25.6 MB
    float* xB   = (float*)(ws + off); off += (size_t)NNODES * 64 * 4;   // 25.6 MB

    hipMemsetAsync(d_ws, 0, zero_bytes, stream);

    count_kernel<<<6250, 256, 0, stream>>>(ei, et, batch, cnt, gcnt);
    scan1_kernel<<<NSCANB, 256, 0, stream>>>(cnt, excl, bsum);
    scan2_kernel<<<1, 512, 0, stream>>>(bsum);
    place_kernel<<<6250, 256, 0, stream>>>(ei, et, excl, bsum, fill, esrc);

    const int GBLK = (NNODES + 63) / 64;   // 1563

    // ---- layer 0: x[38] -> xA ----
    fused_kernel<DIN, true, false><<<GBLK, 1024, 0, stream>>>(
        x, W0, root0, resw, b0, resb, ln0g, ln0b,
        cnt, excl, bsum, esrc, batch, xA);

    // ---- layer 1: xA -> xB ----
    fused_kernel<HID, false, false><<<GBLK, 1024, 0, stream>>>(
        xA, W1, root1, nullptr, b1, nullptr, ln1g, ln1b,
        cnt, excl, bsum, esrc, batch, xB);

    // ---- layer 2: xB -> pooled (fused mean-pool atomics) ----
    fused_kernel<HID, false, true><<<GBLK, 1024, 0, stream>>>(
        xB, W2, root2, nullptr, b2, nullptr, ln2g, ln2b,
        cnt, excl, bsum, esrc, batch, pooled);

    // ---- readout ----
    readout_kernel<<<250, 256, 0, stream>>>(
        pooled, gcnt, row1, rob1, row2, rob2, out);
}

// Round 8
// 717.074 us; speedup vs baseline: 1.3433x; 1.3433x over previous
//
#include <hip/hip_runtime.h>
#include <math.h>

#define NNODES 100000
#define NEDGES 1600000
#define NREL   4
#define DIN    38
#define HID    64
#define NGRAPH 1000
#define NSEG   (NNODES * NREL)          // 400000
#define NSCANB ((NSEG + 1023) / 1024)   // 391
#define YW     320                      // y row width (4 rel slices + root slice)

__device__ __forceinline__ float wsum64(float v) {
    #pragma unroll
    for (int o = 32; o; o >>= 1) v += __shfl_xor(v, o);
    return v;
}

__device__ __forceinline__ void ln_group_reduce(float& s) {
    s += __shfl_xor(s, 1);
    s += __shfl_xor(s, 2);
    s += __shfl_xor(s, 4);
    s += __shfl_xor(s, 8);
}

// ---------------------------------------------------------------------------
// counts: cnt[node*R+rel] edge counts, gcnt[g] nodes per graph
// ---------------------------------------------------------------------------
__global__ __launch_bounds__(256) void count_kernel(
    const int* __restrict__ ei, const int* __restrict__ et,
    const int* __restrict__ batch, int* __restrict__ cnt,
    int* __restrict__ gcnt) {
    int i = blockIdx.x * 256 + threadIdx.x;
    if (i < NEDGES) {
        int dst = ei[NEDGES + i];
        atomicAdd(&cnt[dst * NREL + et[i]], 1);
    }
    if (i < NNODES) {
        atomicAdd(&gcnt[batch[i]], 1);
    }
}

// ---------------------------------------------------------------------------
// scan1: per-1024-chunk exclusive scan of cnt -> excl, chunk totals -> bsum
// ---------------------------------------------------------------------------
__global__ __launch_bounds__(256) void scan1_kernel(
    const int* __restrict__ cnt, int* __restrict__ excl, int* __restrict__ bsum) {
    __shared__ int tmp[256];
    int tid = threadIdx.x;
    int base = blockIdx.x * 1024 + tid * 4;
    int v0 = 0, v1 = 0, v2 = 0, v3 = 0;
    if (base + 0 < NSEG) v0 = cnt[base + 0];
    if (base + 1 < NSEG) v1 = cnt[base + 1];
    if (base + 2 < NSEG) v2 = cnt[base + 2];
    if (base + 3 < NSEG) v3 = cnt[base + 3];
    int s = v0 + v1 + v2 + v3;
    tmp[tid] = s;
    __syncthreads();
    for (int off = 1; off < 256; off <<= 1) {
        int t = (tid >= off) ? tmp[tid - off] : 0;
        __syncthreads();
        tmp[tid] += t;
        __syncthreads();
    }
    if (tid == 255) bsum[blockIdx.x] = tmp[255];
    int run = tmp[tid] - s;
    if (base + 0 < NSEG) excl[base + 0] = run; run += v0;
    if (base + 1 < NSEG) excl[base + 1] = run; run += v1;
    if (base + 2 < NSEG) excl[base + 2] = run; run += v2;
    if (base + 3 < NSEG) excl[base + 3] = run;
}

// scan2: exclusive scan of bsum[NSCANB] in one block
__global__ __launch_bounds__(512) void scan2_kernel(int* __restrict__ bsum) {
    __shared__ int tmp[512];
    int tid = threadIdx.x;
    int v = (tid < NSCANB) ? bsum[tid] : 0;
    tmp[tid] = v;
    __syncthreads();
    for (int off = 1; off < 512; off <<= 1) {
        int t = (tid >= off) ? tmp[tid - off] : 0;
        __syncthreads();
        tmp[tid] += t;
        __syncthreads();
    }
    if (tid < NSCANB) bsum[tid] = tmp[tid] - v;
}

// ---------------------------------------------------------------------------
// place: CSR bucket fill. packed entry = src | (rel << 20)
// ---------------------------------------------------------------------------
__global__ __launch_bounds__(256) void place_kernel(
    const int* __restrict__ ei, const int* __restrict__ et,
    const int* __restrict__ excl, const int* __restrict__ bsum,
    int* __restrict__ fill, int* __restrict__ esrc) {
    int e = blockIdx.x * 256 + threadIdx.x;
    if (e >= NEDGES) return;
    int r = et[e];
    int seg = ei[NEDGES + e] * NREL + r;
    int pos = excl[seg] + bsum[seg >> 10] + atomicAdd(&fill[seg], 1);
    esrc[pos] = ei[e] | (r << 20);
}

// ---------------------------------------------------------------------------
// gemm12: y[n][nc*64+ch] = sum_k x[n][k] * B[k][gc],  B = [W_r0..W_r3 | root]
// ---------------------------------------------------------------------------
__global__ __launch_bounds__(256, 4) void gemm12_kernel(
    const float* __restrict__ x, const float* __restrict__ W,
    const float* __restrict__ root, float* __restrict__ y) {
    __shared__ float As[64][68];
    __shared__ float Ws[64][68];
    int tid = threadIdx.x;
    int nbase = blockIdx.x * 64;

    {   // stage As (full K=64)
        int sk = tid & 63, sm0 = tid >> 6;
        #pragma unroll
        for (int mm = 0; mm < 16; ++mm) {
            int m = sm0 + mm * 4;
            int n = nbase + m; if (n > NNODES - 1) n = NNODES - 1;
            As[sk][m] = x[(size_t)n * 64 + sk];
        }
    }
    int r = tid >> 4, c = tid & 15;
    int scc = tid & 63, sk0 = tid >> 6;

    for (int nc = 0; nc < 5; ++nc) {
        __syncthreads();
        const float* src = (nc < 4) ? (W + nc * 4096) : root;
        #pragma unroll
        for (int kk = 0; kk < 16; ++kk) {
            int k = sk0 + kk * 4;
            Ws[k][scc] = src[k * 64 + scc];
        }
        __syncthreads();
        float acc[4][4] = {};
        #pragma unroll 4
        for (int k = 0; k < 64; ++k) {
            const float4 av = *(const float4*)&As[k][r * 4];
            const float4 wv = *(const float4*)&Ws[k][c * 4];
            const float a_[4] = {av.x, av.y, av.z, av.w};
            const float w_[4] = {wv.x, wv.y, wv.z, wv.w};
            #pragma unroll
            for (int i = 0; i < 4; ++i)
                #pragma unroll
                for (int j = 0; j < 4; ++j)
                    acc[i][j] += a_[i] * w_[j];
        }
        #pragma unroll
        for (int i = 0; i < 4; ++i) {
            int n = nbase + r * 4 + i;
            if (n < NNODES)
                *(float4*)&y[(size_t)n * YW + nc * 64 + c * 4] =
                    make_float4(acc[i][0], acc[i][1], acc[i][2], acc[i][3]);
        }
    }
}

// ---------------------------------------------------------------------------
// gemm0: x [N,38]; chunks 0-3: W0 slices, 4: root0 -> y[N,320];
//        chunk 5: res_w -> xres[N,64]
// ---------------------------------------------------------------------------
__global__ __launch_bounds__(256, 4) void gemm0_kernel(
    const float* __restrict__ x, const float* __restrict__ W0,
    const float* __restrict__ root0, const float* __restrict__ resw,
    float* __restrict__ y, float* __restrict__ xres) {
    __shared__ float As[38][68];
    __shared__ float Ws[38][68];
    int tid = threadIdx.x;
    int nbase = blockIdx.x * 64;

    for (int idx = tid; idx < 64 * 38; idx += 256) {
        int m = idx / 38, k = idx - m * 38;
        int n = nbase + m; if (n > NNODES - 1) n = NNODES - 1;
        As[k][m] = x[(size_t)n * DIN + k];
    }
    int r = tid >> 4, c = tid & 15;

    for (int nc = 0; nc < 6; ++nc) {
        __syncthreads();
        const float* src = (nc < 4) ? (W0 + nc * DIN * 64)
                                    : (nc == 4 ? root0 : resw);
        for (int idx = tid; idx < 38 * 64; idx += 256) {
            int k = idx >> 6, cc = idx & 63;
            Ws[k][cc] = src[idx];
        }
        __syncthreads();
        float acc[4][4] = {};
        #pragma unroll 2
        for (int k = 0; k < 38; ++k) {
            const float4 av = *(const float4*)&As[k][r * 4];
            const float4 wv = *(const float4*)&Ws[k][c * 4];
            const float a_[4] = {av.x, av.y, av.z, av.w};
            const float w_[4] = {wv.x, wv.y, wv.z, wv.w};
            #pragma unroll
            for (int i = 0; i < 4; ++i)
                #pragma unroll
                for (int j = 0; j < 4; ++j)
                    acc[i][j] += a_[i] * w_[j];
        }
        #pragma unroll
        for (int i = 0; i < 4; ++i) {
            int n = nbase + r * 4 + i;
            if (n < NNODES) {
                float4 o = make_float4(acc[i][0], acc[i][1], acc[i][2], acc[i][3]);
                if (nc < 5) *(float4*)&y[(size_t)n * YW + nc * 64 + c * 4] = o;
                else        *(float4*)&xres[(size_t)n * 64 + c * 4] = o;
            }
        }
    }
}

// ---------------------------------------------------------------------------
// epilogue: one wave per node. lane = (q = lane>>4: edge slot, cl = lane&15:
// channel quarter). Staging per 64-edge chunk: moff = src*5+rel (y row-chunk),
// ic = 1/max(cnt[rel],1) pre-scale (0 for invalid). Inner loop: 4-wide
// pipelined float4 gathers (16 edges, 4 loads in flight per lane).
// Cross-quarter shfl_xor reduce, LN in 16-lane groups; FULL-WAVE store:
// lane (q,cl) stores channel cl*4+q (one dword) -> no write amplification.
// ---------------------------------------------------------------------------
template <bool L0, bool POOL>
__global__ __launch_bounds__(256, 8) void epi_kernel(
    const float* __restrict__ y, const float* __restrict__ xprev,
    const int* __restrict__ esrc, const int* __restrict__ excl,
    const int* __restrict__ bsum, const int* __restrict__ cnt,
    const float* __restrict__ bias, const float* __restrict__ bias2,
    const float* __restrict__ lng, const float* __restrict__ lnb,
    const int* __restrict__ batch, float* __restrict__ dst) {
    int n = (blockIdx.x * 256 + threadIdx.x) >> 6;
    int lane = threadIdx.x & 63;
    if (n >= NNODES) return;
    int q = lane >> 4;        // edge slot
    int cl = lane & 15;       // channel quarter

    int s4 = n * 4;
    int myc = 0, myb = 0;
    if (lane < 4) {
        myc = cnt[s4 + lane];
        myb = excl[s4 + lane] + bsum[(s4 + lane) >> 10];
    }
    float myi = 1.f / fmaxf((float)myc, 1.f);
    int c0 = __shfl(myc, 0), c1 = __shfl(myc, 1);
    int c2 = __shfl(myc, 2), c3 = __shfl(myc, 3);
    float i0 = __shfl(myi, 0), i1 = __shfl(myi, 1);
    float i2 = __shfl(myi, 2), i3 = __shfl(myi, 3);
    int beg = __shfl(myb, 0);
    int ctot = c0 + c1 + c2 + c3;

    float acc[4] = {0.f, 0.f, 0.f, 0.f};
    for (int base = 0; base < ctot; base += 64) {
        int rem = ctot - base; if (rem > 64) rem = 64;
        // stage: per-edge row-chunk offset + pre-scale factor
        int raw = (lane < rem) ? esrc[beg + base + lane] : 0;
        int src = raw & 0xFFFFF;
        int rel = raw >> 20;
        int moff = src * 5 + rel;
        float ic = (rel & 2) ? ((rel & 1) ? i3 : i2)
                             : ((rel & 1) ? i1 : i0);
        if (lane >= rem) ic = 0.f;

        int it = (rem + 3) >> 2;   // 4-edge steps
        int i = 0;
        // 4-wide: 16 edges per iteration, 4 independent loads in flight
        for (; i + 4 <= it; i += 4) {
            int l0 = (i + 0) * 4 + q, l1 = (i + 1) * 4 + q;
            int l2 = (i + 2) * 4 + q, l3 = (i + 3) * 4 + q;
            int o0 = __shfl(moff, l0), o1 = __shfl(moff, l1);
            int o2 = __shfl(moff, l2), o3 = __shfl(moff, l3);
            float s0 = __shfl(ic, l0), s1 = __shfl(ic, l1);
            float s2 = __shfl(ic, l2), s3 = __shfl(ic, l3);
            const float4 v0 = *(const float4*)&y[(size_t)o0 * 64 + cl * 4];
            const float4 v1 = *(const float4*)&y[(size_t)o1 * 64 + cl * 4];
            const float4 v2 = *(const float4*)&y[(size_t)o2 * 64 + cl * 4];
            const float4 v3 = *(const float4*)&y[(size_t)o3 * 64 + cl * 4];
            acc[0] += v0.x * s0; acc[1] += v0.y * s0;
            acc[2] += v0.z * s0; acc[3] += v0.w * s0;
            acc[0] += v1.x * s1; acc[1] += v1.y * s1;
            acc[2] += v1.z * s1; acc[3] += v1.w * s1;
            acc[0] += v2.x * s2; acc[1] += v2.y * s2;
            acc[2] += v2.z * s2; acc[3] += v2.w * s2;
            acc[0] += v3.x * s3; acc[1] += v3.y * s3;
            acc[2] += v3.z * s3; acc[3] += v3.w * s3;
        }
        for (; i < it; ++i) {
            int l = i * 4 + q;
            int o = __shfl(moff, l);
            float sc = __shfl(ic, l);
            const float4 v = *(const float4*)&y[(size_t)o * 64 + cl * 4];
            acc[0] += v.x * sc; acc[1] += v.y * sc;
            acc[2] += v.z * sc; acc[3] += v.w * sc;
        }
    }
    // combine edge slots: all lanes end with full channel sums
    #pragma unroll
    for (int j = 0; j < 4; ++j) {
        acc[j] += __shfl_xor(acc[j], 16);
        acc[j] += __shfl_xor(acc[j], 32);
    }

    // epilogue (channels ch = cl*4+j; identical across q)
    const float4 yr = *(const float4*)&y[(size_t)n * YW + 256 + cl * 4];
    const float4 bv = *(const float4*)&bias[cl * 4];
    const float4 rv = *(const float4*)&xprev[(size_t)n * 64 + cl * 4];
    const float y_[4] = {yr.x, yr.y, yr.z, yr.w};
    const float b_[4] = {bv.x, bv.y, bv.z, bv.w};
    const float r_[4] = {rv.x, rv.y, rv.z, rv.w};
    float u[4];
    float s = 0.f;
    #pragma unroll
    for (int j = 0; j < 4; ++j) {
        u[j] = fmaxf(acc[j] + y_[j] + b_[j], 0.f) + r_[j];
        s += u[j];
    }
    if (L0) {
        const float4 sv = *(const float4*)&bias2[cl * 4];
        const float s2_[4] = {sv.x, sv.y, sv.z, sv.w};
        #pragma unroll
        for (int j = 0; j < 4; ++j) { u[j] += s2_[j]; s += s2_[j]; }
    }
    ln_group_reduce(s);
    float mu = s * (1.f / 64.f);
    float qq = 0.f;
    #pragma unroll
    for (int j = 0; j < 4; ++j) { u[j] -= mu; qq += u[j] * u[j]; }
    ln_group_reduce(qq);
    float inv = 1.f / sqrtf(qq * (1.f / 64.f) + 1e-5f);
    const float4 gv = *(const float4*)&lng[cl * 4];
    const float4 ev = *(const float4*)&lnb[cl * 4];
    const float g_[4] = {gv.x, gv.y, gv.z, gv.w};
    const float e_[4] = {ev.x, ev.y, ev.z, ev.w};
    // full-wave store: lane (q,cl) owns channel cl*4+q
    float oq = u[q] * inv * g_[q] + e_[q];
    if (POOL) {
        int g = batch[n];
        atomicAdd(dst + (size_t)g * 64 + cl * 4 + q, oq);
    } else {
        dst[(size_t)n * 64 + cl * 4 + q] = oq;
    }
}

// ---------------------------------------------------------------------------
// readout: out[g] = relu(pooled[g]/cnt @ ro_w1 + ro_b1) @ ro_w2 + ro_b2
// ---------------------------------------------------------------------------
__global__ __launch_bounds__(256) void readout_kernel(
    const float* __restrict__ pooled, const int* __restrict__ gcnt,
    const float* __restrict__ w1, const float* __restrict__ b1,
    const float* __restrict__ w2, const float* __restrict__ b2,
    float* __restrict__ out) {
    __shared__ float wl[64][64];
    int tid = threadIdx.x;
    for (int idx = tid; idx < 64 * 64; idx += 256) {
        wl[idx >> 6][idx & 63] = w1[idx];
    }
    __syncthreads();
    int wv = tid >> 6, lane = tid & 63;
    int g = blockIdx.x * 4 + wv;
    if (g >= NGRAPH) return;
    int cc = gcnt[g];
    float cf = cc > 0 ? (float)cc : 1.0f;
    float p = pooled[(size_t)g * 64 + lane] / cf;
    float acc = b1[lane];
    for (int f = 0; f < 64; ++f) {
        acc += __shfl(p, f) * wl[f][lane];
    }
    float t = fmaxf(acc, 0.f);
    float v = t * w2[lane];
    v = wsum64(v);
    if (lane == 0) out[g] = v + b2[0];
}

// ---------------------------------------------------------------------------
extern "C" void kernel_launch(void* const* d_in, const int* in_sizes, int n_in,
                              void* d_out, int out_size, void* d_ws, size_t ws_size,
                              hipStream_t stream) {
    const float* x     = (const float*)d_in[0];
    const int*   ei    = (const int*)d_in[1];
    const int*   et    = (const int*)d_in[2];
    const int*   batch = (const int*)d_in[3];
    const float* W0    = (const float*)d_in[4];
    const float* root0 = (const float*)d_in[5];
    const float* b0    = (const float*)d_in[6];
    const float* ln0g  = (const float*)d_in[7];
    const float* ln0b  = (const float*)d_in[8];
    const float* resw  = (const float*)d_in[9];
    const float* resb  = (const float*)d_in[10];
    const float* W1    = (const float*)d_in[11];
    const float* root1 = (const float*)d_in[12];
    const float* b1    = (const float*)d_in[13];
    const float* ln1g  = (const float*)d_in[14];
    const float* ln1b  = (const float*)d_in[15];
    const float* W2    = (const float*)d_in[16];
    const float* root2 = (const float*)d_in[17];
    const float* b2    = (const float*)d_in[18];
    const float* ln2g  = (const float*)d_in[19];
    const float* ln2b  = (const float*)d_in[20];
    const float* row1  = (const float*)d_in[21];
    const float* rob1  = (const float*)d_in[22];
    const float* row2  = (const float*)d_in[23];
    const float* rob2  = (const float*)d_in[24];
    float* out = (float*)d_out;

    char* ws = (char*)d_ws;
    size_t off = 0;
    int* cnt    = (int*)(ws + off); off += (size_t)NSEG * 4;            // 1.6 MB
    int* fill   = (int*)(ws + off); off += (size_t)NSEG * 4;            // 1.6 MB
    int* gcnt   = (int*)(ws + off); off += 4096;
    float* pooled = (float*)(ws + off); off += (size_t)NGRAPH * 64 * 4; // 256 KB
    size_t zero_bytes = off;                                            // ~3.46 MB
    int* excl   = (int*)(ws + off); off += (size_t)NSEG * 4;
    int* bsum   = (int*)(ws + off); off += 4096;
    int* esrc   = (int*)(ws + off); off += (size_t)NEDGES * 4;          // 6.4 MB
    float* y    = (float*)(ws + off); off += (size_t)NNODES * YW * 4;   // 128 MB
    float* xA   = (float*)(ws + off); off += (size_t)NNODES * 64 * 4;   // 25.6 MB
    float* xB   = (float*)(ws + off); off += (size_t)NNODES * 64 * 4;   // 25.6 MB

    hipMemsetAsync(d_ws, 0, zero_bytes, stream);

    count_kernel<<<6250, 256, 0, stream>>>(ei, et, batch, cnt, gcnt);
    scan1_kernel<<<NSCANB, 256, 0, stream>>>(cnt, excl, bsum);
    scan2_kernel<<<1, 512, 0, stream>>>(bsum);
    place_kernel<<<6250, 256, 0, stream>>>(ei, et, excl, bsum, fill, esrc);

    const int GBLK = (NNODES + 63) / 64;   // 1563
    const int EBLK = (NNODES + 3) / 4;     // 25000

    // ---- layer 0 ----
    gemm0_kernel<<<GBLK, 256, 0, stream>>>(x, W0, root0, resw, y, xA);
    epi_kernel<true, false><<<EBLK, 256, 0, stream>>>(
        y, xA, esrc, excl, bsum, cnt, b0, resb, ln0g, ln0b, batch, xA);

    // ---- layer 1 ----
    gemm12_kernel<<<GBLK, 256, 0, stream>>>(xA, W1, root1, y);
    epi_kernel<false, false><<<EBLK, 256, 0, stream>>>(
        y, xA, esrc, excl, bsum, cnt, b1, resb, ln1g, ln1b, batch, xB);

    // ---- layer 2 (pool fused) ----
    gemm12_kernel<<<GBLK, 256, 0, stream>>>(xB, W2, root2, y);
    epi_kernel<false, true><<<EBLK, 256, 0, stream>>>(
        y, xB, esrc, excl, bsum, cnt, b2, resb, ln2g, ln2b, batch, pooled);

    // ---- readout ----
    readout_kernel<<<250, 256, 0, stream>>>(
        pooled, gcnt, row1, rob1, row2, rob2, out);
}

// Round 11
// 691.859 us; speedup vs baseline: 1.3923x; 1.0364x over previous
//
#include <hip/hip_runtime.h>
#include <math.h>

#define NNODES 100000
#define NEDGES 1600000
#define NREL   4
#define DIN    38
#define HID    64
#define NGRAPH 1000
#define NSEG   (NNODES * NREL)          // 400000
#define NSCANB ((NSEG + 1023) / 1024)   // 391

__device__ __forceinline__ float wsum64(float v) {
    #pragma unroll
    for (int o = 32; o; o >>= 1) v += __shfl_xor(v, o);
    return v;
}

__device__ __forceinline__ void ln_group_reduce(float& s) {
    s += __shfl_xor(s, 1);
    s += __shfl_xor(s, 2);
    s += __shfl_xor(s, 4);
    s += __shfl_xor(s, 8);
}

// ---------------------------------------------------------------------------
// counts: cnt[node*R+rel] edge counts ONLY (no same-address gcnt atomics)
// ---------------------------------------------------------------------------
__global__ __launch_bounds__(256) void count_kernel(
    const int* __restrict__ ei, const int* __restrict__ et,
    int* __restrict__ cnt) {
    int i = blockIdx.x * 256 + threadIdx.x;
    if (i < NEDGES) {
        int dst = ei[NEDGES + i];
        atomicAdd(&cnt[dst * NREL + et[i]], 1);
    }
}

// ---------------------------------------------------------------------------
// scan1: per-1024-chunk exclusive scan of cnt -> excl, chunk totals -> bsum
// ---------------------------------------------------------------------------
__global__ __launch_bounds__(256) void scan1_kernel(
    const int* __restrict__ cnt, int* __restrict__ excl, int* __restrict__ bsum) {
    __shared__ int tmp[256];
    int tid = threadIdx.x;
    int base = blockIdx.x * 1024 + tid * 4;
    int v0 = 0, v1 = 0, v2 = 0, v3 = 0;
    if (base + 0 < NSEG) v0 = cnt[base + 0];
    if (base + 1 < NSEG) v1 = cnt[base + 1];
    if (base + 2 < NSEG) v2 = cnt[base + 2];
    if (base + 3 < NSEG) v3 = cnt[base + 3];
    int s = v0 + v1 + v2 + v3;
    tmp[tid] = s;
    __syncthreads();
    for (int off = 1; off < 256; off <<= 1) {
        int t = (tid >= off) ? tmp[tid - off] : 0;
        __syncthreads();
        tmp[tid] += t;
        __syncthreads();
    }
    if (tid == 255) bsum[blockIdx.x] = tmp[255];
    int run = tmp[tid] - s;
    if (base + 0 < NSEG) excl[base + 0] = run; run += v0;
    if (base + 1 < NSEG) excl[base + 1] = run; run += v1;
    if (base + 2 < NSEG) excl[base + 2] = run; run += v2;
    if (base + 3 < NSEG) excl[base + 3] = run;
}

// scan2: exclusive scan of bsum[NSCANB] in one block
__global__ __launch_bounds__(512) void scan2_kernel(int* __restrict__ bsum) {
    __shared__ int tmp[512];
    int tid = threadIdx.x;
    int v = (tid < NSCANB) ? bsum[tid] : 0;
    tmp[tid] = v;
    __syncthreads();
    for (int off = 1; off < 512; off <<= 1) {
        int t = (tid >= off) ? tmp[tid - off] : 0;
        __syncthreads();
        tmp[tid] += t;
        __syncthreads();
    }
    if (tid < NSCANB) bsum[tid] = tmp[tid] - v;
}

// ---------------------------------------------------------------------------
// place: CSR bucket fill. packed entry = src | (rel << 20)
// ---------------------------------------------------------------------------
__global__ __launch_bounds__(256) void place_kernel(
    const int* __restrict__ ei, const int* __restrict__ et,
    const int* __restrict__ excl, const int* __restrict__ bsum,
    int* __restrict__ fill, int* __restrict__ esrc) {
    int e = blockIdx.x * 256 + threadIdx.x;
    if (e >= NEDGES) return;
    int r = et[e];
    int seg = ei[NEDGES + e] * NREL + r;
    int pos = excl[seg] + bsum[seg >> 10] + atomicAdd(&fill[seg], 1);
    esrc[pos] = ei[e] | (r << 20);
}

// ---------------------------------------------------------------------------
// gemm12: y[n][rel*64+ch] (gathered part, 256-wide) ; yroot[n][ch] (streamed)
// ---------------------------------------------------------------------------
__global__ __launch_bounds__(256, 4) void gemm12_kernel(
    const float* __restrict__ x, const float* __restrict__ W,
    const float* __restrict__ root, float* __restrict__ y,
    float* __restrict__ yroot) {
    __shared__ float As[64][68];
    __shared__ float Ws[64][68];
    int tid = threadIdx.x;
    int nbase = blockIdx.x * 64;

    {   // stage As (full K=64)
        int sk = tid & 63, sm0 = tid >> 6;
        #pragma unroll
        for (int mm = 0; mm < 16; ++mm) {
            int m = sm0 + mm * 4;
            int n = nbase + m; if (n > NNODES - 1) n = NNODES - 1;
            As[sk][m] = x[(size_t)n * 64 + sk];
        }
    }
    int r = tid >> 4, c = tid & 15;
    int scc = tid & 63, sk0 = tid >> 6;

    for (int nc = 0; nc < 5; ++nc) {
        __syncthreads();
        const float* src = (nc < 4) ? (W + nc * 4096) : root;
        #pragma unroll
        for (int kk = 0; kk < 16; ++kk) {
            int k = sk0 + kk * 4;
            Ws[k][scc] = src[k * 64 + scc];
        }
        __syncthreads();
        float acc[4][4] = {};
        #pragma unroll 4
        for (int k = 0; k < 64; ++k) {
            const float4 av = *(const float4*)&As[k][r * 4];
            const float4 wv = *(const float4*)&Ws[k][c * 4];
            const float a_[4] = {av.x, av.y, av.z, av.w};
            const float w_[4] = {wv.x, wv.y, wv.z, wv.w};
            #pragma unroll
            for (int i = 0; i < 4; ++i)
                #pragma unroll
                for (int j = 0; j < 4; ++j)
                    acc[i][j] += a_[i] * w_[j];
        }
        #pragma unroll
        for (int i = 0; i < 4; ++i) {
            int n = nbase + r * 4 + i;
            if (n < NNODES) {
                float4 o = make_float4(acc[i][0], acc[i][1], acc[i][2], acc[i][3]);
                if (nc < 4) *(float4*)&y[(size_t)n * 256 + nc * 64 + c * 4] = o;
                else        *(float4*)&yroot[(size_t)n * 64 + c * 4] = o;
            }
        }
    }
}

// ---------------------------------------------------------------------------
// gemm0: x [N,38]; chunks 0-3: W0 -> y[N,256]; 4: root0 -> yroot; 5: res_w -> xres
// ---------------------------------------------------------------------------
__global__ __launch_bounds__(256, 4) void gemm0_kernel(
    const float* __restrict__ x, const float* __restrict__ W0,
    const float* __restrict__ root0, const float* __restrict__ resw,
    float* __restrict__ y, float* __restrict__ yroot, float* __restrict__ xres) {
    __shared__ float As[38][68];
    __shared__ float Ws[38][68];
    int tid = threadIdx.x;
    int nbase = blockIdx.x * 64;

    for (int idx = tid; idx < 64 * 38; idx += 256) {
        int m = idx / 38, k = idx - m * 38;
        int n = nbase + m; if (n > NNODES - 1) n = NNODES - 1;
        As[k][m] = x[(size_t)n * DIN + k];
    }
    int r = tid >> 4, c = tid & 15;

    for (int nc = 0; nc < 6; ++nc) {
        __syncthreads();
        const float* src = (nc < 4) ? (W0 + nc * DIN * 64)
                                    : (nc == 4 ? root0 : resw);
        for (int idx = tid; idx < 38 * 64; idx += 256) {
            int k = idx >> 6, cc = idx & 63;
            Ws[k][cc] = src[idx];
        }
        __syncthreads();
        float acc[4][4] = {};
        #pragma unroll 2
        for (int k = 0; k < 38; ++k) {
            const float4 av = *(const float4*)&As[k][r * 4];
            const float4 wv = *(const float4*)&Ws[k][c * 4];
            const float a_[4] = {av.x, av.y, av.z, av.w};
            const float w_[4] = {wv.x, wv.y, wv.z, wv.w};
            #pragma unroll
            for (int i = 0; i < 4; ++i)
                #pragma unroll
                for (int j = 0; j < 4; ++j)
                    acc[i][j] += a_[i] * w_[j];
        }
        #pragma unroll
        for (int i = 0; i < 4; ++i) {
            int n = nbase + r * 4 + i;
            if (n < NNODES) {
                float4 o = make_float4(acc[i][0], acc[i][1], acc[i][2], acc[i][3]);
                if (nc < 4)      *(float4*)&y[(size_t)n * 256 + nc * 64 + c * 4] = o;
                else if (nc == 4) *(float4*)&yroot[(size_t)n * 64 + c * 4] = o;
                else             *(float4*)&xres[(size_t)n * 64 + c * 4] = o;
            }
        }
    }
}

// ---------------------------------------------------------------------------
// epilogue: one wave per node. lane = (q = lane>>4: edge slot, cl = lane&15:
// channel quarter). moff = src*4+rel (compact 102.4MB gather buffer),
// ic = 1/max(cnt[rel],1) pre-scale. 4-wide pipelined float4 gathers.
// Cross-quarter shfl_xor reduce, LN in 16-lane groups; full-wave dword store.
// ---------------------------------------------------------------------------
template <bool L0>
__global__ __launch_bounds__(256, 8) void epi_kernel(
    const float* __restrict__ y, const float* __restrict__ yroot,
    const float* __restrict__ xprev,
    const int* __restrict__ esrc, const int* __restrict__ excl,
    const int* __restrict__ bsum, const int* __restrict__ cnt,
    const float* __restrict__ bias, const float* __restrict__ bias2,
    const float* __restrict__ lng, const float* __restrict__ lnb,
    float* __restrict__ dst) {
    int n = (blockIdx.x * 256 + threadIdx.x) >> 6;
    int lane = threadIdx.x & 63;
    if (n >= NNODES) return;
    int q = lane >> 4;        // edge slot
    int cl = lane & 15;       // channel quarter

    int s4 = n * 4;
    int myc = 0, myb = 0;
    if (lane < 4) {
        myc = cnt[s4 + lane];
        myb = excl[s4 + lane] + bsum[(s4 + lane) >> 10];
    }
    float myi = 1.f / fmaxf((float)myc, 1.f);
    int c0 = __shfl(myc, 0), c1 = __shfl(myc, 1);
    int c2 = __shfl(myc, 2), c3 = __shfl(myc, 3);
    float i0 = __shfl(myi, 0), i1 = __shfl(myi, 1);
    float i2 = __shfl(myi, 2), i3 = __shfl(myi, 3);
    int beg = __shfl(myb, 0);
    int ctot = c0 + c1 + c2 + c3;

    float acc[4] = {0.f, 0.f, 0.f, 0.f};
    for (int base = 0; base < ctot; base += 64) {
        int rem = ctot - base; if (rem > 64) rem = 64;
        int raw = (lane < rem) ? esrc[beg + base + lane] : 0;
        int src = raw & 0xFFFFF;
        int rel = raw >> 20;
        int moff = src * 4 + rel;
        float ic = (rel & 2) ? ((rel & 1) ? i3 : i2)
                             : ((rel & 1) ? i1 : i0);
        if (lane >= rem) ic = 0.f;

        int it = (rem + 3) >> 2;   // 4-edge steps
        int i = 0;
        for (; i + 4 <= it; i += 4) {
            int l0 = (i + 0) * 4 + q, l1 = (i + 1) * 4 + q;
            int l2 = (i + 2) * 4 + q, l3 = (i + 3) * 4 + q;
            int o0 = __shfl(moff, l0), o1 = __shfl(moff, l1);
            int o2 = __shfl(moff, l2), o3 = __shfl(moff, l3);
            float s0 = __shfl(ic, l0), s1 = __shfl(ic, l1);
            float s2 = __shfl(ic, l2), s3 = __shfl(ic, l3);
            const float4 v0 = *(const float4*)&y[(size_t)o0 * 64 + cl * 4];
            const float4 v1 = *(const float4*)&y[(size_t)o1 * 64 + cl * 4];
            const float4 v2 = *(const float4*)&y[(size_t)o2 * 64 + cl * 4];
            const float4 v3 = *(const float4*)&y[(size_t)o3 * 64 + cl * 4];
            acc[0] += v0.x * s0; acc[1] += v0.y * s0;
            acc[2] += v0.z * s0; acc[3] += v0.w * s0;
            acc[0] += v1.x * s1; acc[1] += v1.y * s1;
            acc[2] += v1.z * s1; acc[3] += v1.w * s1;
            acc[0] += v2.x * s2; acc[1] += v2.y * s2;
            acc[2] += v2.z * s2; acc[3] += v2.w * s2;
            acc[0] += v3.x * s3; acc[1] += v3.y * s3;
            acc[2] += v3.z * s3; acc[3] += v3.w * s3;
        }
        for (; i < it; ++i) {
            int l = i * 4 + q;
            int o = __shfl(moff, l);
            float sc = __shfl(ic, l);
            const float4 v = *(const float4*)&y[(size_t)o * 64 + cl * 4];
            acc[0] += v.x * sc; acc[1] += v.y * sc;
            acc[2] += v.z * sc; acc[3] += v.w * sc;
        }
    }
    #pragma unroll
    for (int j = 0; j < 4; ++j) {
        acc[j] += __shfl_xor(acc[j], 16);
        acc[j] += __shfl_xor(acc[j], 32);
    }

    // epilogue (channels ch = cl*4+j; identical across q)
    const float4 yr = *(const float4*)&yroot[(size_t)n * 64 + cl * 4];
    const float4 bv = *(const float4*)&bias[cl * 4];
    const float4 rv = *(const float4*)&xprev[(size_t)n * 64 + cl * 4];
    const float y_[4] = {yr.x, yr.y, yr.z, yr.w};
    const float b_[4] = {bv.x, bv.y, bv.z, bv.w};
    const float r_[4] = {rv.x, rv.y, rv.z, rv.w};
    float u[4];
    float s = 0.f;
    #pragma unroll
    for (int j = 0; j < 4; ++j) {
        u[j] = fmaxf(acc[j] + y_[j] + b_[j], 0.f) + r_[j];
        s += u[j];
    }
    if (L0) {
        const float4 sv = *(const float4*)&bias2[cl * 4];
        const float s2_[4] = {sv.x, sv.y, sv.z, sv.w};
        #pragma unroll
        for (int j = 0; j < 4; ++j) { u[j] += s2_[j]; s += s2_[j]; }
    }
    ln_group_reduce(s);
    float mu = s * (1.f / 64.f);
    float qq = 0.f;
    #pragma unroll
    for (int j = 0; j < 4; ++j) { u[j] -= mu; qq += u[j] * u[j]; }
    ln_group_reduce(qq);
    float inv = 1.f / sqrtf(qq * (1.f / 64.f) + 1e-5f);
    const float4 gv = *(const float4*)&lng[cl * 4];
    const float4 ev = *(const float4*)&lnb[cl * 4];
    const float g_[4] = {gv.x, gv.y, gv.z, gv.w};
    const float e_[4] = {ev.x, ev.y, ev.z, ev.w};
    // full-wave store: lane (q,cl) owns channel cl*4+q
    float oq = u[q] * inv * g_[q] + e_[q];
    dst[(size_t)n * 64 + cl * 4 + q] = oq;
}

// ---------------------------------------------------------------------------
// readout: per-graph mean over the CONTIGUOUS node range (batch is sorted),
// found by binary search — no atomics, no gcnt. Then 2-layer MLP.
// One wave per graph, lane = hidden channel.
// ---------------------------------------------------------------------------
__global__ __launch_bounds__(256) void readout_kernel(
    const float* __restrict__ xfin, const int* __restrict__ batch,
    const float* __restrict__ w1, const float* __restrict__ b1,
    const float* __restrict__ w2, const float* __restrict__ b2,
    float* __restrict__ out) {
    __shared__ float wl[64][64];
    int tid = threadIdx.x;
    for (int idx = tid; idx < 64 * 64; idx += 256) {
        wl[idx >> 6][idx & 63] = w1[idx];
    }
    __syncthreads();
    int wv = tid >> 6, lane = tid & 63;
    int g = blockIdx.x * 4 + wv;
    if (g >= NGRAPH) return;
    // lb = lower_bound(batch, g), ub = lower_bound(batch, g+1)
    int lo = 0, hi = NNODES;
    while (lo < hi) { int mid = (lo + hi) >> 1; if (batch[mid] < g) lo = mid + 1; else hi = mid; }
    int lb = lo;
    hi = NNODES;
    while (lo < hi) { int mid = (lo + hi) >> 1; if (batch[mid] < g + 1) lo = mid + 1; else hi = mid; }
    int ub = lo;
    float s0 = 0.f, s1 = 0.f, s2 = 0.f, s3 = 0.f;
    int n2 = lb;
    for (; n2 + 4 <= ub; n2 += 4) {
        s0 += xfin[(size_t)(n2 + 0) * 64 + lane];
        s1 += xfin[(size_t)(n2 + 1) * 64 + lane];
        s2 += xfin[(size_t)(n2 + 2) * 64 + lane];
        s3 += xfin[(size_t)(n2 + 3) * 64 + lane];
    }
    for (; n2 < ub; ++n2) s0 += xfin[(size_t)n2 * 64 + lane];
    float p = (s0 + s1 + s2 + s3) / fmaxf((float)(ub - lb), 1.f);
    float acc = b1[lane];
    for (int f = 0; f < 64; ++f) {
        acc += __shfl(p, f) * wl[f][lane];
    }
    float t = fmaxf(acc, 0.f);
    float v = t * w2[lane];
    v = wsum64(v);
    if (lane == 0) out[g] = v + b2[0];
}

// ---------------------------------------------------------------------------
extern "C" void kernel_launch(void* const* d_in, const int* in_sizes, int n_in,
                              void* d_out, int out_size, void* d_ws, size_t ws_size,
                              hipStream_t stream) {
    const float* x     = (const float*)d_in[0];
    const int*   ei    = (const int*)d_in[1];
    const int*   et    = (const int*)d_in[2];
    const int*   batch = (const int*)d_in[3];
    const float* W0    = (const float*)d_in[4];
    const float* root0 = (const float*)d_in[5];
    const float* b0    = (const float*)d_in[6];
    const float* ln0g  = (const float*)d_in[7];
    const float* ln0b  = (const float*)d_in[8];
    const float* resw  = (const float*)d_in[9];
    const float* resb  = (const float*)d_in[10];
    const float* W1    = (const float*)d_in[11];
    const float* root1 = (const float*)d_in[12];
    const float* b1    = (const float*)d_in[13];
    const float* ln1g  = (const float*)d_in[14];
    const float* ln1b  = (const float*)d_in[15];
    const float* W2    = (const float*)d_in[16];
    const float* root2 = (const float*)d_in[17];
    const float* b2    = (const float*)d_in[18];
    const float* ln2g  = (const float*)d_in[19];
    const float* ln2b  = (const float*)d_in[20];
    const float* row1  = (const float*)d_in[21];
    const float* rob1  = (const float*)d_in[22];
    const float* row2  = (const float*)d_in[23];
    const float* rob2  = (const float*)d_in[24];
    float* out = (float*)d_out;

    char* ws = (char*)d_ws;
    size_t off = 0;
    int* cnt    = (int*)(ws + off); off += (size_t)NSEG * 4;            // 1.6 MB
    int* fill   = (int*)(ws + off); off += (size_t)NSEG * 4;            // 1.6 MB
    size_t zero_bytes = off;                                            // 3.2 MB
    int* excl   = (int*)(ws + off); off += (size_t)NSEG * 4;
    int* bsum   = (int*)(ws + off); off += 4096;
    int* esrc   = (int*)(ws + off); off += (size_t)NEDGES * 4;          // 6.4 MB
    float* y    = (float*)(ws + off); off += (size_t)NNODES * 256 * 4;  // 102.4 MB
    float* yroot= (float*)(ws + off); off += (size_t)NNODES * 64 * 4;   // 25.6 MB
    float* xA   = (float*)(ws + off); off += (size_t)NNODES * 64 * 4;   // 25.6 MB
    float* xB   = (float*)(ws + off); off += (size_t)NNODES * 64 * 4;   // 25.6 MB

    hipMemsetAsync(d_ws, 0, zero_bytes, stream);

    count_kernel<<<6250, 256, 0, stream>>>(ei, et, cnt);
    scan1_kernel<<<NSCANB, 256, 0, stream>>>(cnt, excl, bsum);
    scan2_kernel<<<1, 512, 0, stream>>>(bsum);
    place_kernel<<<6250, 256, 0, stream>>>(ei, et, excl, bsum, fill, esrc);

    const int GBLK = (NNODES + 63) / 64;   // 1563
    const int EBLK = (NNODES + 3) / 4;     // 25000

    // ---- layer 0: gemm0 -> (y, yroot, xres=xA); epi -> xA ----
    gemm0_kernel<<<GBLK, 256, 0, stream>>>(x, W0, root0, resw, y, yroot, xA);
    epi_kernel<true><<<EBLK, 256, 0, stream>>>(
        y, yroot, xA, esrc, excl, bsum, cnt, b0, resb, ln0g, ln0b, xA);

    // ---- layer 1: xA -> xB ----
    gemm12_kernel<<<GBLK, 256, 0, stream>>>(xA, W1, root1, y, yroot);
    epi_kernel<false><<<EBLK, 256, 0, stream>>>(
        y, yroot, xA, esrc, excl, bsum, cnt, b1, resb, ln1g, ln1b, xB);

    // ---- layer 2: xB -> xA (no atomics; pooling moved to readout) ----
    gemm12_kernel<<<GBLK, 256, 0, stream>>>(xB, W2, root2, y, yroot);
    epi_kernel<false><<<EBLK, 256, 0, stream>>>(
        y, yroot, xB, esrc, excl, bsum, cnt, b2, resb, ln2g, ln2b, xA);

    // ---- readout: pool from xA (sorted batch, contiguous ranges) + MLP ----
    readout_kernel<<<250, 256, 0, stream>>>(
        xA, batch, row1, rob1, row2, rob2, out);
}

// Round 12
// 594.506 us; speedup vs baseline: 1.6203x; 1.1638x over previous
//
#include <hip/hip_runtime.h>
#include <math.h>

#define NNODES 100000
#define NEDGES 1600000
#define NREL   4
#define DIN    38
#define HID    64
#define NGRAPH 1000
#define NSEG   (NNODES * NREL)          // 400000
#define NSCANB ((NSEG + 1023) / 1024)   // 391
#define CBLK   6250                     // count blocks in fused0

__device__ __forceinline__ float wsum64(float v) {
    #pragma unroll
    for (int o = 32; o; o >>= 1) v += __shfl_xor(v, o);
    return v;
}

__device__ __forceinline__ void ln_group_reduce(float& s) {
    s += __shfl_xor(s, 1);
    s += __shfl_xor(s, 2);
    s += __shfl_xor(s, 4);
    s += __shfl_xor(s, 8);
}

// bf16 helpers (RNE)
__device__ __forceinline__ unsigned short f2bf(float f) {
    unsigned u = __float_as_uint(f);
    return (unsigned short)((u + 0x7FFFu + ((u >> 16) & 1u)) >> 16);
}
__device__ __forceinline__ float bf2f(unsigned short b) {
    return __uint_as_float(((unsigned)b) << 16);
}

// ---------------------------------------------------------------------------
// fused0: blocks [0,CBLK) = count+rank; blocks [CBLK,..) = gemm0.
// count: rank[e] = atomicAdd(cnt[dst*R+rel], 1)  (rank reused by place)
// gemm0: x[N,38] -> y bf16 [N,256] (W0), yroot f32 (root0), xres f32 (res_w)
// ---------------------------------------------------------------------------
__global__ __launch_bounds__(256, 4) void fused0_kernel(
    const int* __restrict__ ei, const int* __restrict__ et,
    int* __restrict__ cnt, int* __restrict__ rank,
    const float* __restrict__ x, const float* __restrict__ W0,
    const float* __restrict__ root0, const float* __restrict__ resw,
    unsigned short* __restrict__ y, float* __restrict__ yroot,
    float* __restrict__ xres) {
    __shared__ float As[38][68];
    __shared__ float Ws[38][68];

    if (blockIdx.x < CBLK) {
        int i = blockIdx.x * 256 + threadIdx.x;
        if (i < NEDGES) {
            int dst = ei[NEDGES + i];
            rank[i] = atomicAdd(&cnt[dst * NREL + et[i]], 1);
        }
        return;
    }

    int tid = threadIdx.x;
    int nbase = (blockIdx.x - CBLK) * 64;

    for (int idx = tid; idx < 64 * 38; idx += 256) {
        int m = idx / 38, k = idx - m * 38;
        int n = nbase + m; if (n > NNODES - 1) n = NNODES - 1;
        As[k][m] = x[(size_t)n * DIN + k];
    }
    int r = tid >> 4, c = tid & 15;

    for (int nc = 0; nc < 6; ++nc) {
        __syncthreads();
        const float* src = (nc < 4) ? (W0 + nc * DIN * 64)
                                    : (nc == 4 ? root0 : resw);
        for (int idx = tid; idx < 38 * 64; idx += 256) {
            int k = idx >> 6, cc = idx & 63;
            Ws[k][cc] = src[idx];
        }
        __syncthreads();
        float acc[4][4] = {};
        #pragma unroll 2
        for (int k = 0; k < 38; ++k) {
            const float4 av = *(const float4*)&As[k][r * 4];
            const float4 wv = *(const float4*)&Ws[k][c * 4];
            const float a_[4] = {av.x, av.y, av.z, av.w};
            const float w_[4] = {wv.x, wv.y, wv.z, wv.w};
            #pragma unroll
            for (int i = 0; i < 4; ++i)
                #pragma unroll
                for (int j = 0; j < 4; ++j)
                    acc[i][j] += a_[i] * w_[j];
        }
        #pragma unroll
        for (int i = 0; i < 4; ++i) {
            int n = nbase + r * 4 + i;
            if (n < NNODES) {
                if (nc < 4) {
                    ushort4 o;
                    o.x = f2bf(acc[i][0]); o.y = f2bf(acc[i][1]);
                    o.z = f2bf(acc[i][2]); o.w = f2bf(acc[i][3]);
                    *(ushort4*)&y[(size_t)n * 256 + nc * 64 + c * 4] = o;
                } else {
                    float4 o = make_float4(acc[i][0], acc[i][1], acc[i][2], acc[i][3]);
                    if (nc == 4) *(float4*)&yroot[(size_t)n * 64 + c * 4] = o;
                    else         *(float4*)&xres[(size_t)n * 64 + c * 4] = o;
                }
            }
        }
    }
}

// ---------------------------------------------------------------------------
// scan1: per-1024-chunk exclusive scan of cnt -> excl, chunk totals -> bsum
// ---------------------------------------------------------------------------
__global__ __launch_bounds__(256) void scan1_kernel(
    const int* __restrict__ cnt, int* __restrict__ excl, int* __restrict__ bsum) {
    __shared__ int tmp[256];
    int tid = threadIdx.x;
    int base = blockIdx.x * 1024 + tid * 4;
    int v0 = 0, v1 = 0, v2 = 0, v3 = 0;
    if (base + 0 < NSEG) v0 = cnt[base + 0];
    if (base + 1 < NSEG) v1 = cnt[base + 1];
    if (base + 2 < NSEG) v2 = cnt[base + 2];
    if (base + 3 < NSEG) v3 = cnt[base + 3];
    int s = v0 + v1 + v2 + v3;
    tmp[tid] = s;
    __syncthreads();
    for (int off = 1; off < 256; off <<= 1) {
        int t = (tid >= off) ? tmp[tid - off] : 0;
        __syncthreads();
        tmp[tid] += t;
        __syncthreads();
    }
    if (tid == 255) bsum[blockIdx.x] = tmp[255];
    int run = tmp[tid] - s;
    if (base + 0 < NSEG) excl[base + 0] = run; run += v0;
    if (base + 1 < NSEG) excl[base + 1] = run; run += v1;
    if (base + 2 < NSEG) excl[base + 2] = run; run += v2;
    if (base + 3 < NSEG) excl[base + 3] = run;
}

// scan2: exclusive scan of bsum[NSCANB] in one block
__global__ __launch_bounds__(512) void scan2_kernel(int* __restrict__ bsum) {
    __shared__ int tmp[512];
    int tid = threadIdx.x;
    int v = (tid < NSCANB) ? bsum[tid] : 0;
    tmp[tid] = v;
    __syncthreads();
    for (int off = 1; off < 512; off <<= 1) {
        int t = (tid >= off) ? tmp[tid - off] : 0;
        __syncthreads();
        tmp[tid] += t;
        __syncthreads();
    }
    if (tid < NSCANB) bsum[tid] = tmp[tid] - v;
}

// ---------------------------------------------------------------------------
// place: atomic-free CSR fill using precomputed rank. entry = src | (rel<<20)
// ---------------------------------------------------------------------------
__global__ __launch_bounds__(256) void place_kernel(
    const int* __restrict__ ei, const int* __restrict__ et,
    const int* __restrict__ excl, const int* __restrict__ bsum,
    const int* __restrict__ rank, int* __restrict__ esrc) {
    int e = blockIdx.x * 256 + threadIdx.x;
    if (e >= NEDGES) return;
    int r = et[e];
    int seg = ei[NEDGES + e] * NREL + r;
    int pos = excl[seg] + bsum[seg >> 10] + rank[e];
    esrc[pos] = ei[e] | (r << 20);
}

// ---------------------------------------------------------------------------
// gemm12: y bf16 [n][rel*64+ch] (gathered), yroot f32 (streamed)
// ---------------------------------------------------------------------------
__global__ __launch_bounds__(256, 4) void gemm12_kernel(
    const float* __restrict__ x, const float* __restrict__ W,
    const float* __restrict__ root, unsigned short* __restrict__ y,
    float* __restrict__ yroot) {
    __shared__ float As[64][68];
    __shared__ float Ws[64][68];
    int tid = threadIdx.x;
    int nbase = blockIdx.x * 64;

    {   // stage As (full K=64)
        int sk = tid & 63, sm0 = tid >> 6;
        #pragma unroll
        for (int mm = 0; mm < 16; ++mm) {
            int m = sm0 + mm * 4;
            int n = nbase + m; if (n > NNODES - 1) n = NNODES - 1;
            As[sk][m] = x[(size_t)n * 64 + sk];
        }
    }
    int r = tid >> 4, c = tid & 15;
    int scc = tid & 63, sk0 = tid >> 6;

    for (int nc = 0; nc < 5; ++nc) {
        __syncthreads();
        const float* src = (nc < 4) ? (W + nc * 4096) : root;
        #pragma unroll
        for (int kk = 0; kk < 16; ++kk) {
            int k = sk0 + kk * 4;
            Ws[k][scc] = src[k * 64 + scc];
        }
        __syncthreads();
        float acc[4][4] = {};
        #pragma unroll 4
        for (int k = 0; k < 64; ++k) {
            const float4 av = *(const float4*)&As[k][r * 4];
            const float4 wv = *(const float4*)&Ws[k][c * 4];
            const float a_[4] = {av.x, av.y, av.z, av.w};
            const float w_[4] = {wv.x, wv.y, wv.z, wv.w};
            #pragma unroll
            for (int i = 0; i < 4; ++i)
                #pragma unroll
                for (int j = 0; j < 4; ++j)
                    acc[i][j] += a_[i] * w_[j];
        }
        #pragma unroll
        for (int i = 0; i < 4; ++i) {
            int n = nbase + r * 4 + i;
            if (n < NNODES) {
                if (nc < 4) {
                    ushort4 o;
                    o.x = f2bf(acc[i][0]); o.y = f2bf(acc[i][1]);
                    o.z = f2bf(acc[i][2]); o.w = f2bf(acc[i][3]);
                    *(ushort4*)&y[(size_t)n * 256 + nc * 64 + c * 4] = o;
                } else {
                    *(float4*)&yroot[(size_t)n * 64 + c * 4] =
                        make_float4(acc[i][0], acc[i][1], acc[i][2], acc[i][3]);
                }
            }
        }
    }
}

// ---------------------------------------------------------------------------
// epilogue: one wave per node. lane = (q = lane>>4: edge slot, cl = lane&15:
// channel quarter). moff = src*4+rel (bf16 gather buffer, 51.2 MB),
// ic = 1/max(cnt[rel],1) pre-scale. 4-wide pipelined ushort4 (bf16x4) gathers.
// Cross-quarter shfl_xor reduce, LN in 16-lane groups; full-wave dword store.
// ---------------------------------------------------------------------------
template <bool L0>
__global__ __launch_bounds__(256, 8) void epi_kernel(
    const unsigned short* __restrict__ y, const float* __restrict__ yroot,
    const float* __restrict__ xprev,
    const int* __restrict__ esrc, const int* __restrict__ excl,
    const int* __restrict__ bsum, const int* __restrict__ cnt,
    const float* __restrict__ bias, const float* __restrict__ bias2,
    const float* __restrict__ lng, const float* __restrict__ lnb,
    float* __restrict__ dst) {
    int n = (blockIdx.x * 256 + threadIdx.x) >> 6;
    int lane = threadIdx.x & 63;
    if (n >= NNODES) return;
    int q = lane >> 4;        // edge slot
    int cl = lane & 15;       // channel quarter

    int s4 = n * 4;
    int myc = 0, myb = 0;
    if (lane < 4) {
        myc = cnt[s4 + lane];
        myb = excl[s4 + lane] + bsum[(s4 + lane) >> 10];
    }
    float myi = 1.f / fmaxf((float)myc, 1.f);
    int c0 = __shfl(myc, 0), c1 = __shfl(myc, 1);
    int c2 = __shfl(myc, 2), c3 = __shfl(myc, 3);
    float i0 = __shfl(myi, 0), i1 = __shfl(myi, 1);
    float i2 = __shfl(myi, 2), i3 = __shfl(myi, 3);
    int beg = __shfl(myb, 0);
    int ctot = c0 + c1 + c2 + c3;

    float acc[4] = {0.f, 0.f, 0.f, 0.f};
    for (int base = 0; base < ctot; base += 64) {
        int rem = ctot - base; if (rem > 64) rem = 64;
        int raw = (lane < rem) ? esrc[beg + base + lane] : 0;
        int src = raw & 0xFFFFF;
        int rel = raw >> 20;
        int moff = src * 4 + rel;
        float ic = (rel & 2) ? ((rel & 1) ? i3 : i2)
                             : ((rel & 1) ? i1 : i0);
        if (lane >= rem) ic = 0.f;

        int it = (rem + 3) >> 2;   // 4-edge steps
        int i = 0;
        for (; i + 4 <= it; i += 4) {
            int l0 = (i + 0) * 4 + q, l1 = (i + 1) * 4 + q;
            int l2 = (i + 2) * 4 + q, l3 = (i + 3) * 4 + q;
            int o0 = __shfl(moff, l0), o1 = __shfl(moff, l1);
            int o2 = __shfl(moff, l2), o3 = __shfl(moff, l3);
            float s0 = __shfl(ic, l0), s1 = __shfl(ic, l1);
            float s2 = __shfl(ic, l2), s3 = __shfl(ic, l3);
            const ushort4 v0 = *(const ushort4*)&y[(size_t)o0 * 64 + cl * 4];
            const ushort4 v1 = *(const ushort4*)&y[(size_t)o1 * 64 + cl * 4];
            const ushort4 v2 = *(const ushort4*)&y[(size_t)o2 * 64 + cl * 4];
            const ushort4 v3 = *(const ushort4*)&y[(size_t)o3 * 64 + cl * 4];
            acc[0] += bf2f(v0.x) * s0; acc[1] += bf2f(v0.y) * s0;
            acc[2] += bf2f(v0.z) * s0; acc[3] += bf2f(v0.w) * s0;
            acc[0] += bf2f(v1.x) * s1; acc[1] += bf2f(v1.y) * s1;
            acc[2] += bf2f(v1.z) * s1; acc[3] += bf2f(v1.w) * s1;
            acc[0] += bf2f(v2.x) * s2; acc[1] += bf2f(v2.y) * s2;
            acc[2] += bf2f(v2.z) * s2; acc[3] += bf2f(v2.w) * s2;
            acc[0] += bf2f(v3.x) * s3; acc[1] += bf2f(v3.y) * s3;
            acc[2] += bf2f(v3.z) * s3; acc[3] += bf2f(v3.w) * s3;
        }
        for (; i < it; ++i) {
            int l = i * 4 + q;
            int o = __shfl(moff, l);
            float sc = __shfl(ic, l);
            const ushort4 v = *(const ushort4*)&y[(size_t)o * 64 + cl * 4];
            acc[0] += bf2f(v.x) * sc; acc[1] += bf2f(v.y) * sc;
            acc[2] += bf2f(v.z) * sc; acc[3] += bf2f(v.w) * sc;
        }
    }
    #pragma unroll
    for (int j = 0; j < 4; ++j) {
        acc[j] += __shfl_xor(acc[j], 16);
        acc[j] += __shfl_xor(acc[j], 32);
    }

    // epilogue (channels ch = cl*4+j; identical across q)
    const float4 yr = *(const float4*)&yroot[(size_t)n * 64 + cl * 4];
    const float4 bv = *(const float4*)&bias[cl * 4];
    const float4 rv = *(const float4*)&xprev[(size_t)n * 64 + cl * 4];
    const float y_[4] = {yr.x, yr.y, yr.z, yr.w};
    const float b_[4] = {bv.x, bv.y, bv.z, bv.w};
    const float r_[4] = {rv.x, rv.y, rv.z, rv.w};
    float u[4];
    float s = 0.f;
    #pragma unroll
    for (int j = 0; j < 4; ++j) {
        u[j] = fmaxf(acc[j] + y_[j] + b_[j], 0.f) + r_[j];
        s += u[j];
    }
    if (L0) {
        const float4 sv = *(const float4*)&bias2[cl * 4];
        const float s2_[4] = {sv.x, sv.y, sv.z, sv.w};
        #pragma unroll
        for (int j = 0; j < 4; ++j) { u[j] += s2_[j]; s += s2_[j]; }
    }
    ln_group_reduce(s);
    float mu = s * (1.f / 64.f);
    float qq = 0.f;
    #pragma unroll
    for (int j = 0; j < 4; ++j) { u[j] -= mu; qq += u[j] * u[j]; }
    ln_group_reduce(qq);
    float inv = 1.f / sqrtf(qq * (1.f / 64.f) + 1e-5f);
    const float4 gv = *(const float4*)&lng[cl * 4];
    const float4 ev = *(const float4*)&lnb[cl * 4];
    const float g_[4] = {gv.x, gv.y, gv.z, gv.w};
    const float e_[4] = {ev.x, ev.y, ev.z, ev.w};
    // full-wave store: lane (q,cl) owns channel cl*4+q
    float oq = u[q] * inv * g_[q] + e_[q];
    dst[(size_t)n * 64 + cl * 4 + q] = oq;
}

// ---------------------------------------------------------------------------
// readout: per-graph mean over the CONTIGUOUS node range (batch is sorted),
// found by binary search — no atomics. Then 2-layer MLP.
// ---------------------------------------------------------------------------
__global__ __launch_bounds__(256) void readout_kernel(
    const float* __restrict__ xfin, const int* __restrict__ batch,
    const float* __restrict__ w1, const float* __restrict__ b1,
    const float* __restrict__ w2, const float* __restrict__ b2,
    float* __restrict__ out) {
    __shared__ float wl[64][64];
    int tid = threadIdx.x;
    for (int idx = tid; idx < 64 * 64; idx += 256) {
        wl[idx >> 6][idx & 63] = w1[idx];
    }
    __syncthreads();
    int wv = tid >> 6, lane = tid & 63;
    int g = blockIdx.x * 4 + wv;
    if (g >= NGRAPH) return;
    int lo = 0, hi = NNODES;
    while (lo < hi) { int mid = (lo + hi) >> 1; if (batch[mid] < g) lo = mid + 1; else hi = mid; }
    int lb = lo;
    hi = NNODES;
    while (lo < hi) { int mid = (lo + hi) >> 1; if (batch[mid] < g + 1) lo = mid + 1; else hi = mid; }
    int ub = lo;
    float s0 = 0.f, s1 = 0.f, s2 = 0.f, s3 = 0.f;
    int n2 = lb;
    for (; n2 + 4 <= ub; n2 += 4) {
        s0 += xfin[(size_t)(n2 + 0) * 64 + lane];
        s1 += xfin[(size_t)(n2 + 1) * 64 + lane];
        s2 += xfin[(size_t)(n2 + 2) * 64 + lane];
        s3 += xfin[(size_t)(n2 + 3) * 64 + lane];
    }
    for (; n2 < ub; ++n2) s0 += xfin[(size_t)n2 * 64 + lane];
    float p = (s0 + s1 + s2 + s3) / fmaxf((float)(ub - lb), 1.f);
    float acc = b1[lane];
    for (int f = 0; f < 64; ++f) {
        acc += __shfl(p, f) * wl[f][lane];
    }
    float t = fmaxf(acc, 0.f);
    float v = t * w2[lane];
    v = wsum64(v);
    if (lane == 0) out[g] = v + b2[0];
}

// ---------------------------------------------------------------------------
extern "C" void kernel_launch(void* const* d_in, const int* in_sizes, int n_in,
                              void* d_out, int out_size, void* d_ws, size_t ws_size,
                              hipStream_t stream) {
    const float* x     = (const float*)d_in[0];
    const int*   ei    = (const int*)d_in[1];
    const int*   et    = (const int*)d_in[2];
    const int*   batch = (const int*)d_in[3];
    const float* W0    = (const float*)d_in[4];
    const float* root0 = (const float*)d_in[5];
    const float* b0    = (const float*)d_in[6];
    const float* ln0g  = (const float*)d_in[7];
    const float* ln0b  = (const float*)d_in[8];
    const float* resw  = (const float*)d_in[9];
    const float* resb  = (const float*)d_in[10];
    const float* W1    = (const float*)d_in[11];
    const float* root1 = (const float*)d_in[12];
    const float* b1    = (const float*)d_in[13];
    const float* ln1g  = (const float*)d_in[14];
    const float* ln1b  = (const float*)d_in[15];
    const float* W2    = (const float*)d_in[16];
    const float* root2 = (const float*)d_in[17];
    const float* b2    = (const float*)d_in[18];
    const float* ln2g  = (const float*)d_in[19];
    const float* ln2b  = (const float*)d_in[20];
    const float* row1  = (const float*)d_in[21];
    const float* rob1  = (const float*)d_in[22];
    const float* row2  = (const float*)d_in[23];
    const float* rob2  = (const float*)d_in[24];
    float* out = (float*)d_out;

    char* ws = (char*)d_ws;
    size_t off = 0;
    int* cnt    = (int*)(ws + off); off += (size_t)NSEG * 4;            // 1.6 MB (zeroed)
    size_t zero_bytes = off;
    int* excl   = (int*)(ws + off); off += (size_t)NSEG * 4;            // 1.6 MB
    int* bsum   = (int*)(ws + off); off += 4096;
    int* rank   = (int*)(ws + off); off += (size_t)NEDGES * 4;          // 6.4 MB
    int* esrc   = (int*)(ws + off); off += (size_t)NEDGES * 4;          // 6.4 MB
    unsigned short* y = (unsigned short*)(ws + off);
    off += (size_t)NNODES * 256 * 2;                                    // 51.2 MB (bf16)
    float* yroot= (float*)(ws + off); off += (size_t)NNODES * 64 * 4;   // 25.6 MB
    float* xA   = (float*)(ws + off); off += (size_t)NNODES * 64 * 4;   // 25.6 MB
    float* xB   = (float*)(ws + off); off += (size_t)NNODES * 64 * 4;   // 25.6 MB

    hipMemsetAsync(d_ws, 0, zero_bytes, stream);

    const int GBLK = (NNODES + 63) / 64;   // 1563
    const int EBLK = (NNODES + 3) / 4;     // 25000

    // ---- layer 0 GEMM + edge count/rank, one dispatch (independent work) ----
    fused0_kernel<<<CBLK + GBLK, 256, 0, stream>>>(
        ei, et, cnt, rank, x, W0, root0, resw, y, yroot, xA);

    scan1_kernel<<<NSCANB, 256, 0, stream>>>(cnt, excl, bsum);
    scan2_kernel<<<1, 512, 0, stream>>>(bsum);
    place_kernel<<<6250, 256, 0, stream>>>(ei, et, excl, bsum, rank, esrc);

    // ---- layer 0 epilogue -> xA ----
    epi_kernel<true><<<EBLK, 256, 0, stream>>>(
        y, yroot, xA, esrc, excl, bsum, cnt, b0, resb, ln0g, ln0b, xA);

    // ---- layer 1: xA -> xB ----
    gemm12_kernel<<<GBLK, 256, 0, stream>>>(xA, W1, root1, y, yroot);
    epi_kernel<false><<<EBLK, 256, 0, stream>>>(
        y, yroot, xA, esrc, excl, bsum, cnt, b1, resb, ln1g, ln1b, xB);

    // ---- layer 2: xB -> xA ----
    gemm12_kernel<<<GBLK, 256, 0, stream>>>(xB, W2, root2, y, yroot);
    epi_kernel<false><<<EBLK, 256, 0, stream>>>(
        y, yroot, xB, esrc, excl, bsum, cnt, b2, resb, ln2g, ln2b, xA);

    // ---- readout ----
    readout_kernel<<<250, 256, 0, stream>>>(
        xA, batch, row1, rob1, row2, rob2, out);
}